// Round 1
// baseline (2317.774 us; speedup 1.0000x reference)
//
#include <hip/hip_runtime.h>
#include <hip/hip_bf16.h>

#define H_DIM 2048
#define I_DIM 1408
#define E_NUM 8
#define N_TOK 1024
#define ISH   2816

#define BM 64
#define BO 64
#define BK 32

// ---------------------------------------------------------------- utilities

__global__ void zero_counts_kernel(int* counts) {
  if (threadIdx.x < E_NUM) counts[threadIdx.x] = 0;
}

// ---------------------------------------------------------------- router
// One wave per token: logits over 8 experts, softmax, top-2, norm, bucket.
__global__ __launch_bounds__(256) void router_kernel(
    const float* __restrict__ x, const float* __restrict__ gate_w,
    int* __restrict__ counts, int* __restrict__ etok, float* __restrict__ ewt) {
  int token = blockIdx.x * 4 + (threadIdx.x >> 6);
  int lane  = threadIdx.x & 63;
  const float* xr = x + (size_t)token * H_DIM;
  float xs[H_DIM / 64];
#pragma unroll
  for (int j = 0; j < H_DIM / 64; ++j) xs[j] = xr[lane + 64 * j];
  float logits[E_NUM];
#pragma unroll
  for (int e = 0; e < E_NUM; ++e) {
    const float* w = gate_w + (size_t)e * H_DIM;
    float s = 0.f;
#pragma unroll
    for (int j = 0; j < H_DIM / 64; ++j) s += xs[j] * w[lane + 64 * j];
#pragma unroll
    for (int off = 32; off > 0; off >>= 1) s += __shfl_down(s, off, 64);
    logits[e] = s;  // valid on lane 0
  }
  if (lane == 0) {
    float mx = logits[0];
    for (int e = 1; e < E_NUM; ++e) mx = fmaxf(mx, logits[e]);
    float p[E_NUM], se = 0.f;
    for (int e = 0; e < E_NUM; ++e) { p[e] = expf(logits[e] - mx); se += p[e]; }
    float inv_se = 1.f / se;
    for (int e = 0; e < E_NUM; ++e) p[e] *= inv_se;
    int i0 = 0;
    for (int e = 1; e < E_NUM; ++e) if (p[e] > p[i0]) i0 = e;
    int i1 = (i0 == 0) ? 1 : 0;
    for (int e = 0; e < E_NUM; ++e) { if (e == i0) continue; if (p[e] > p[i1]) i1 = e; }
    float w0 = p[i0], w1 = p[i1];
    float inv = 1.f / (w0 + w1 + 1e-20f);
    w0 *= inv; w1 *= inv;
    int s0 = atomicAdd(&counts[i0], 1);
    etok[i0 * N_TOK + s0] = token; ewt[i0 * N_TOK + s0] = w0;
    int s1 = atomicAdd(&counts[i1], 1);
    etok[i1 * N_TOK + s1] = token; ewt[i1 * N_TOK + s1] = w1;
  }
}

// ------------------------------------------------- LDS tile store (transposed)
__device__ __forceinline__ void store_tile_t(float dst[BK][BM], int lr, int lc,
                                             const float* __restrict__ p) {
  float4 v0 = *(const float4*)p;
  float4 v1 = *(const float4*)(p + 4);
  dst[lc + 0][lr] = v0.x; dst[lc + 1][lr] = v0.y;
  dst[lc + 2][lr] = v0.z; dst[lc + 3][lr] = v0.w;
  dst[lc + 4][lr] = v1.x; dst[lc + 5][lr] = v1.y;
  dst[lc + 6][lr] = v1.z; dst[lc + 7][lr] = v1.w;
}

// ---------------------------------------------------------------- shared gate/up
// act[t][o] = silu(x.sg_o) * (x.su_o); M=1024, O=2816, K=2048
__global__ __launch_bounds__(256) void shared_gateup_kernel(
    const float* __restrict__ x, const float* __restrict__ sg,
    const float* __restrict__ su, float* __restrict__ act) {
  __shared__ float Xs[BK][BM];
  __shared__ float Gs[BK][BO];
  __shared__ float Us[BK][BO];
  int tid = threadIdx.x;
  int m0 = blockIdx.x * BM, o0 = blockIdx.y * BO;
  int lr = tid >> 2, lc = (tid & 3) * 8;
  int tx = tid & 15, ty = tid >> 4;
  const float* xrow = x  + (size_t)(m0 + lr) * H_DIM + lc;
  const float* grow = sg + (size_t)(o0 + lr) * H_DIM + lc;
  const float* urow = su + (size_t)(o0 + lr) * H_DIM + lc;
  float accg[4][4] = {}, accu[4][4] = {};
  for (int k0 = 0; k0 < H_DIM; k0 += BK) {
    __syncthreads();
    store_tile_t(Xs, lr, lc, xrow + k0);
    store_tile_t(Gs, lr, lc, grow + k0);
    store_tile_t(Us, lr, lc, urow + k0);
    __syncthreads();
#pragma unroll 8
    for (int k = 0; k < BK; ++k) {
      float4 a = *(const float4*)&Xs[k][ty * 4];
      float4 g = *(const float4*)&Gs[k][tx * 4];
      float4 u = *(const float4*)&Us[k][tx * 4];
      float av[4] = {a.x, a.y, a.z, a.w};
      float gv[4] = {g.x, g.y, g.z, g.w};
      float uv[4] = {u.x, u.y, u.z, u.w};
#pragma unroll
      for (int i = 0; i < 4; ++i)
#pragma unroll
        for (int j = 0; j < 4; ++j) {
          accg[i][j] = fmaf(av[i], gv[j], accg[i][j]);
          accu[i][j] = fmaf(av[i], uv[j], accu[i][j]);
        }
    }
  }
#pragma unroll
  for (int i = 0; i < 4; ++i) {
    int t = m0 + ty * 4 + i;
    float* dst = act + (size_t)t * ISH + o0 + tx * 4;
#pragma unroll
    for (int j = 0; j < 4; ++j) {
      float g = accg[i][j], u = accu[i][j];
      dst[j] = (g / (1.f + expf(-g))) * u;
    }
  }
}

// ---------------------------------------------------------------- routed gate/up
__global__ __launch_bounds__(256) void routed_gateup_kernel(
    const float* __restrict__ x, const float* __restrict__ eg,
    const float* __restrict__ eu, const int* __restrict__ counts,
    const int* __restrict__ etok, float* __restrict__ act) {
  int e = blockIdx.z;
  int cnt = counts[e];
  int m0 = blockIdx.x * BM;
  if (m0 >= cnt) return;
  __shared__ float Xs[BK][BM];
  __shared__ float Gs[BK][BO];
  __shared__ float Us[BK][BO];
  int tid = threadIdx.x;
  int o0 = blockIdx.y * BO;
  int lr = tid >> 2, lc = (tid & 3) * 8;
  int tx = tid & 15, ty = tid >> 4;
  int row = m0 + lr;
  int tok = etok[e * N_TOK + ((row < cnt) ? row : 0)];
  const float* xrow = x + (size_t)tok * H_DIM + lc;
  const float* grow = eg + ((size_t)e * I_DIM + o0 + lr) * H_DIM + lc;
  const float* urow = eu + ((size_t)e * I_DIM + o0 + lr) * H_DIM + lc;
  float accg[4][4] = {}, accu[4][4] = {};
  for (int k0 = 0; k0 < H_DIM; k0 += BK) {
    __syncthreads();
    store_tile_t(Xs, lr, lc, xrow + k0);
    store_tile_t(Gs, lr, lc, grow + k0);
    store_tile_t(Us, lr, lc, urow + k0);
    __syncthreads();
#pragma unroll 8
    for (int k = 0; k < BK; ++k) {
      float4 a = *(const float4*)&Xs[k][ty * 4];
      float4 g = *(const float4*)&Gs[k][tx * 4];
      float4 u = *(const float4*)&Us[k][tx * 4];
      float av[4] = {a.x, a.y, a.z, a.w};
      float gv[4] = {g.x, g.y, g.z, g.w};
      float uv[4] = {u.x, u.y, u.z, u.w};
#pragma unroll
      for (int i = 0; i < 4; ++i)
#pragma unroll
        for (int j = 0; j < 4; ++j) {
          accg[i][j] = fmaf(av[i], gv[j], accg[i][j]);
          accu[i][j] = fmaf(av[i], uv[j], accu[i][j]);
        }
    }
  }
#pragma unroll
  for (int i = 0; i < 4; ++i) {
    int slot = m0 + ty * 4 + i;
    if (slot >= cnt) continue;
    float* dst = act + ((size_t)e * N_TOK + slot) * I_DIM + o0 + tx * 4;
#pragma unroll
    for (int j = 0; j < 4; ++j) {
      float g = accg[i][j], u = accu[i][j];
      dst[j] = (g / (1.f + expf(-g))) * u;
    }
  }
}

// ---------------------------------------------------------------- shared down
// out[t][h] = act_sh . sd_h ; M=1024, O=2048, K=2816 (writes out, no accumulate)
__global__ __launch_bounds__(256) void shared_down_kernel(
    const float* __restrict__ act, const float* __restrict__ sd,
    float* __restrict__ out) {
  __shared__ float Xs[BK][BM];
  __shared__ float Ws[BK][BO];
  int tid = threadIdx.x;
  int m0 = blockIdx.x * BM, o0 = blockIdx.y * BO;
  int lr = tid >> 2, lc = (tid & 3) * 8;
  int tx = tid & 15, ty = tid >> 4;
  const float* xrow = act + (size_t)(m0 + lr) * ISH + lc;
  const float* wrow = sd  + (size_t)(o0 + lr) * ISH + lc;
  float acc[4][4] = {};
  for (int k0 = 0; k0 < ISH; k0 += BK) {
    __syncthreads();
    store_tile_t(Xs, lr, lc, xrow + k0);
    store_tile_t(Ws, lr, lc, wrow + k0);
    __syncthreads();
#pragma unroll 8
    for (int k = 0; k < BK; ++k) {
      float4 a = *(const float4*)&Xs[k][ty * 4];
      float4 b = *(const float4*)&Ws[k][tx * 4];
      float av[4] = {a.x, a.y, a.z, a.w};
      float bv[4] = {b.x, b.y, b.z, b.w};
#pragma unroll
      for (int i = 0; i < 4; ++i)
#pragma unroll
        for (int j = 0; j < 4; ++j)
          acc[i][j] = fmaf(av[i], bv[j], acc[i][j]);
    }
  }
#pragma unroll
  for (int i = 0; i < 4; ++i) {
    int t = m0 + ty * 4 + i;
    float* dst = out + (size_t)t * H_DIM + o0 + tx * 4;
#pragma unroll
    for (int j = 0; j < 4; ++j) dst[j] = acc[i][j];
  }
}

// ---------------------------------------------------------------- routed down
// out[tok][h] += w_slot * (act_r[slot] . ed_h)
__global__ __launch_bounds__(256) void routed_down_kernel(
    const float* __restrict__ act, const float* __restrict__ ed,
    const int* __restrict__ counts, const int* __restrict__ etok,
    const float* __restrict__ ewt, float* __restrict__ out) {
  int e = blockIdx.z;
  int cnt = counts[e];
  int m0 = blockIdx.x * BM;
  if (m0 >= cnt) return;
  __shared__ float Xs[BK][BM];
  __shared__ float Ws[BK][BO];
  int tid = threadIdx.x;
  int o0 = blockIdx.y * BO;
  int lr = tid >> 2, lc = (tid & 3) * 8;
  int tx = tid & 15, ty = tid >> 4;
  int row = m0 + lr;
  int srow = (row < cnt) ? row : 0;
  const float* xrow = act + ((size_t)e * N_TOK + srow) * I_DIM + lc;
  const float* wrow = ed  + ((size_t)e * H_DIM + o0 + lr) * I_DIM + lc;
  float acc[4][4] = {};
  for (int k0 = 0; k0 < I_DIM; k0 += BK) {
    __syncthreads();
    store_tile_t(Xs, lr, lc, xrow + k0);
    store_tile_t(Ws, lr, lc, wrow + k0);
    __syncthreads();
#pragma unroll 8
    for (int k = 0; k < BK; ++k) {
      float4 a = *(const float4*)&Xs[k][ty * 4];
      float4 b = *(const float4*)&Ws[k][tx * 4];
      float av[4] = {a.x, a.y, a.z, a.w};
      float bv[4] = {b.x, b.y, b.z, b.w};
#pragma unroll
      for (int i = 0; i < 4; ++i)
#pragma unroll
        for (int j = 0; j < 4; ++j)
          acc[i][j] = fmaf(av[i], bv[j], acc[i][j]);
    }
  }
#pragma unroll
  for (int i = 0; i < 4; ++i) {
    int slot = m0 + ty * 4 + i;
    if (slot >= cnt) continue;
    int tok = etok[e * N_TOK + slot];
    float wt = ewt[e * N_TOK + slot];
    float* dst = out + (size_t)tok * H_DIM + o0 + tx * 4;
#pragma unroll
    for (int j = 0; j < 4; ++j)
      atomicAdd(&dst[j], wt * acc[i][j]);
  }
}

// ---------------------------------------------------------------- launch

extern "C" void kernel_launch(void* const* d_in, const int* in_sizes, int n_in,
                              void* d_out, int out_size, void* d_ws, size_t ws_size,
                              hipStream_t stream) {
  const float* x      = (const float*)d_in[0];
  const float* gate_w = (const float*)d_in[1];
  const float* eg     = (const float*)d_in[2];
  const float* eu     = (const float*)d_in[3];
  const float* ed     = (const float*)d_in[4];
  const float* sg     = (const float*)d_in[5];
  const float* su     = (const float*)d_in[6];
  const float* sd     = (const float*)d_in[7];
  float* out = (float*)d_out;

  char* ws = (char*)d_ws;
  int*   counts = (int*)ws;                                    // 32 B
  int*   etok   = (int*)(ws + 1024);                           // 32 KiB
  float* ewt    = (float*)(ws + 1024 + E_NUM * N_TOK * 4);     // 32 KiB
  float* act_sh = (float*)(ws + (1 << 17));                    // 1024*2816*4 = 11.5 MB
  float* act_r  = (float*)(ws + (1 << 17) + (size_t)N_TOK * ISH * 4);  // 8*1024*1408*4 = 46 MB

  zero_counts_kernel<<<1, 64, 0, stream>>>(counts);
  router_kernel<<<N_TOK / 4, 256, 0, stream>>>(x, gate_w, counts, etok, ewt);
  shared_gateup_kernel<<<dim3(N_TOK / BM, ISH / BO), 256, 0, stream>>>(x, sg, su, act_sh);
  routed_gateup_kernel<<<dim3(N_TOK / BM, I_DIM / BO, E_NUM), 256, 0, stream>>>(
      x, eg, eu, counts, etok, act_r);
  shared_down_kernel<<<dim3(N_TOK / BM, H_DIM / BO), 256, 0, stream>>>(act_sh, sd, out);
  routed_down_kernel<<<dim3(N_TOK / BM, H_DIM / BO, E_NUM), 256, 0, stream>>>(
      act_r, ed, counts, etok, ewt, out);
}

// Round 2
// 1040.790 us; speedup vs baseline: 2.2269x; 2.2269x over previous
//
#include <hip/hip_runtime.h>
#include <hip/hip_bf16.h>

#define H_DIM 2048
#define I_DIM 1408
#define E_NUM 8
#define N_TOK 1024
#define ISH   2816

typedef short bf16x8 __attribute__((ext_vector_type(8)));
typedef float f32x4  __attribute__((ext_vector_type(4)));

#define MFMA16(a, b, c) __builtin_amdgcn_mfma_f32_16x16x32_bf16((a), (b), (c), 0, 0, 0)

// ---- split-fp32 helpers: value = hi(bf16, truncated) + lo(bf16, truncated) ----
// packed plane format: one uint per element, high 16 = hi bits, low 16 = lo bits.

__device__ __forceinline__ uint pack_split_f32(float f) {
  uint b = __float_as_uint(f);
  uint h = b & 0xffff0000u;
  float lo = f - __uint_as_float(h);   // exact
  return h | (__float_as_uint(lo) >> 16);
}

// two packed elements -> one uint of 2 hi-bf16, one uint of 2 lo-bf16
__device__ __forceinline__ void unpack_pair(uint v0, uint v1, uint& hp, uint& lp) {
  hp = (v0 >> 16) | (v1 & 0xffff0000u);
  lp = (v0 & 0x0000ffffu) | (v1 << 16);
}

// two fp32 -> hi-pair / lo-pair bf16 uints
__device__ __forceinline__ void split_pair(float f0, float f1, uint& hp, uint& lp) {
  uint b0 = __float_as_uint(f0), b1 = __float_as_uint(f1);
  uint h0 = b0 & 0xffff0000u, h1 = b1 & 0xffff0000u;
  float l0 = f0 - __uint_as_float(h0);
  float l1 = f1 - __uint_as_float(h1);
  hp = (b0 >> 16) | h1;
  lp = (__float_as_uint(l0) >> 16) | (__float_as_uint(l1) & 0xffff0000u);
}

__device__ __forceinline__ void unpack8(uint4 a, uint4 b, uint4& H, uint4& L) {
  unpack_pair(a.x, a.y, H.x, L.x);
  unpack_pair(a.z, a.w, H.y, L.y);
  unpack_pair(b.x, b.y, H.z, L.z);
  unpack_pair(b.z, b.w, H.w, L.w);
}

__device__ __forceinline__ void split8(float4 a, float4 b, uint4& H, uint4& L) {
  split_pair(a.x, a.y, H.x, L.x);
  split_pair(a.z, a.w, H.y, L.y);
  split_pair(b.x, b.y, H.z, L.z);
  split_pair(b.z, b.w, H.w, L.w);
}

union FragU { uint4 u; bf16x8 f; };
__device__ __forceinline__ bf16x8 ldfrag(const uint* p) {
  FragU x; x.u = *(const uint4*)p; return x.f;
}

// ---------------------------------------------------------------- tiny kernels

__global__ void zero_counts_kernel(int* counts) {
  if (threadIdx.x < E_NUM) counts[threadIdx.x] = 0;
}

__global__ void prefix_kernel(const int* __restrict__ counts, int* __restrict__ offsets) {
  if (threadIdx.x == 0) {
    int s = 0;
    for (int e = 0; e < E_NUM; ++e) { offsets[e] = s; s += counts[e]; }
  }
}

__global__ __launch_bounds__(256) void split_x_kernel(
    const float* __restrict__ x, uint* __restrict__ px) {
  int i = blockIdx.x * 256 + threadIdx.x;  // 4 elements per thread
  float4 v = ((const float4*)x)[i];
  uint4 o;
  o.x = pack_split_f32(v.x); o.y = pack_split_f32(v.y);
  o.z = pack_split_f32(v.z); o.w = pack_split_f32(v.w);
  ((uint4*)px)[i] = o;
}

// ---------------------------------------------------------------- router
__global__ __launch_bounds__(256) void router_kernel(
    const float* __restrict__ x, const float* __restrict__ gate_w,
    int* __restrict__ counts, int* __restrict__ etok, float* __restrict__ ewt) {
  int token = blockIdx.x * 4 + (threadIdx.x >> 6);
  int lane  = threadIdx.x & 63;
  const float* xr = x + (size_t)token * H_DIM;
  float xs[H_DIM / 64];
#pragma unroll
  for (int j = 0; j < H_DIM / 64; ++j) xs[j] = xr[lane + 64 * j];
  float logits[E_NUM];
#pragma unroll
  for (int e = 0; e < E_NUM; ++e) {
    const float* w = gate_w + (size_t)e * H_DIM;
    float s = 0.f;
#pragma unroll
    for (int j = 0; j < H_DIM / 64; ++j) s += xs[j] * w[lane + 64 * j];
#pragma unroll
    for (int off = 32; off > 0; off >>= 1) s += __shfl_down(s, off, 64);
    logits[e] = s;
  }
  if (lane == 0) {
    float mx = logits[0];
    for (int e = 1; e < E_NUM; ++e) mx = fmaxf(mx, logits[e]);
    float p[E_NUM], se = 0.f;
    for (int e = 0; e < E_NUM; ++e) { p[e] = expf(logits[e] - mx); se += p[e]; }
    float inv_se = 1.f / se;
    for (int e = 0; e < E_NUM; ++e) p[e] *= inv_se;
    int i0 = 0;
    for (int e = 1; e < E_NUM; ++e) if (p[e] > p[i0]) i0 = e;
    int i1 = (i0 == 0) ? 1 : 0;
    for (int e = 0; e < E_NUM; ++e) { if (e == i0) continue; if (p[e] > p[i1]) i1 = e; }
    float w0 = p[i0], w1 = p[i1];
    float inv = 1.f / (w0 + w1 + 1e-20f);
    w0 *= inv; w1 *= inv;
    int s0 = atomicAdd(&counts[i0], 1);
    etok[i0 * N_TOK + s0] = token; ewt[i0 * N_TOK + s0] = w0;
    int s1 = atomicAdd(&counts[i1], 1);
    etok[i1 * N_TOK + s1] = token; ewt[i1 * N_TOK + s1] = w1;
  }
}

// ---------------------------------------------------------------- gate/up MFMA
// Block: 128 tokens x 64 output cols, computing BOTH g and u, fused silu*u.
// A from pre-split packed plane px (gathered for routed); B(g,u) split in-kernel.
// Output: packed split plane act[(base+slot)*ncols + n].
template<bool GATHER>
__global__ __launch_bounds__(256) void gateup_kernel(
    const uint* __restrict__ px, const float* __restrict__ wgq,
    const float* __restrict__ wuq, const int* __restrict__ counts,
    const int* __restrict__ offsets, const int* __restrict__ etok,
    uint* __restrict__ act, int ncols) {
  int e = GATHER ? blockIdx.z : 0;
  int cnt = GATHER ? counts[e] : N_TOK;
  int m0 = blockIdx.x * 128;
  if (m0 >= cnt) return;
  int o0 = blockIdx.y * 64;

  __shared__ uint Ah[128][20], Al[128][20];   // stride 20 -> conflict-free b128
  __shared__ uint Bh[2][64][20], Bl[2][64][20];

  int tid = threadIdx.x;
  // staging roles: 2 threads/row for A (16 elems each), g/u halves for B
  int arow = tid >> 1, ahalf = tid & 1;
  int srow = m0 + arow;
  int tokrow;
  if (GATHER) tokrow = etok[e * N_TOK + (srow < cnt ? srow : 0)];
  else        tokrow = srow;
  const uint* aptr = px + (size_t)tokrow * H_DIM + ahalf * 16;

  int bw = tid >> 7, brow = (tid >> 1) & 63, bhalf = tid & 1;
  const float* wsel = bw ? wuq : wgq;
  if (GATHER) wsel += (size_t)e * I_DIM * H_DIM;
  const float* bptr = wsel + (size_t)(o0 + brow) * H_DIM + bhalf * 16;

  int w = tid >> 6, wr = w >> 1, wc = w & 1;
  int l = tid & 63, lr = l & 15, lk = l >> 4;

  f32x4 zf = {0.f, 0.f, 0.f, 0.f};
  f32x4 accg[4][2], accu[4][2];
#pragma unroll
  for (int mi = 0; mi < 4; ++mi)
#pragma unroll
    for (int ni = 0; ni < 2; ++ni) { accg[mi][ni] = zf; accu[mi][ni] = zf; }

  uint4 areg[4]; float4 breg[4];
#pragma unroll
  for (int q = 0; q < 4; ++q) {
    areg[q] = *(const uint4*)(aptr + q * 4);
    breg[q] = *(const float4*)(bptr + q * 4);
  }

  for (int k0 = 0; k0 < H_DIM; k0 += 32) {
    __syncthreads();
    {
      uint4 H0, L0, H1, L1;
      unpack8(areg[0], areg[1], H0, L0);
      unpack8(areg[2], areg[3], H1, L1);
      *(uint4*)&Ah[arow][ahalf * 8]     = H0;
      *(uint4*)&Ah[arow][ahalf * 8 + 4] = H1;
      *(uint4*)&Al[arow][ahalf * 8]     = L0;
      *(uint4*)&Al[arow][ahalf * 8 + 4] = L1;
      uint4 BH0, BL0, BH1, BL1;
      split8(breg[0], breg[1], BH0, BL0);
      split8(breg[2], breg[3], BH1, BL1);
      *(uint4*)&Bh[bw][brow][bhalf * 8]     = BH0;
      *(uint4*)&Bh[bw][brow][bhalf * 8 + 4] = BH1;
      *(uint4*)&Bl[bw][brow][bhalf * 8]     = BL0;
      *(uint4*)&Bl[bw][brow][bhalf * 8 + 4] = BL1;
    }
    __syncthreads();
    if (k0 + 32 < H_DIM) {
#pragma unroll
      for (int q = 0; q < 4; ++q) {
        areg[q] = *(const uint4*)(aptr + k0 + 32 + q * 4);
        breg[q] = *(const float4*)(bptr + k0 + 32 + q * 4);
      }
    }
    bf16x8 ah[4], al[4];
#pragma unroll
    for (int mi = 0; mi < 4; ++mi) {
      ah[mi] = ldfrag(&Ah[wr * 64 + mi * 16 + lr][lk * 4]);
      al[mi] = ldfrag(&Al[wr * 64 + mi * 16 + lr][lk * 4]);
    }
#pragma unroll
    for (int ni = 0; ni < 2; ++ni) {
      int br = wc * 32 + ni * 16 + lr;
      bf16x8 bgh = ldfrag(&Bh[0][br][lk * 4]);
      bf16x8 bgl = ldfrag(&Bl[0][br][lk * 4]);
      bf16x8 buh = ldfrag(&Bh[1][br][lk * 4]);
      bf16x8 bul = ldfrag(&Bl[1][br][lk * 4]);
#pragma unroll
      for (int mi = 0; mi < 4; ++mi) {
        accg[mi][ni] = MFMA16(ah[mi], bgh, accg[mi][ni]);
        accu[mi][ni] = MFMA16(ah[mi], buh, accu[mi][ni]);
        accg[mi][ni] = MFMA16(ah[mi], bgl, accg[mi][ni]);
        accu[mi][ni] = MFMA16(ah[mi], bul, accu[mi][ni]);
        accg[mi][ni] = MFMA16(al[mi], bgh, accg[mi][ni]);
        accu[mi][ni] = MFMA16(al[mi], buh, accu[mi][ni]);
      }
    }
  }

  int base_out = GATHER ? offsets[e] : 0;
#pragma unroll
  for (int mi = 0; mi < 4; ++mi) {
#pragma unroll
    for (int ni = 0; ni < 2; ++ni) {
      int n = o0 + wc * 32 + ni * 16 + lr;
#pragma unroll
      for (int r = 0; r < 4; ++r) {
        int mm = m0 + wr * 64 + mi * 16 + lk * 4 + r;
        if (GATHER && mm >= cnt) continue;
        float g = accg[mi][ni][r], u = accu[mi][ni][r];
        float a = (g / (1.f + __expf(-g))) * u;  // silu(g)*u
        act[(size_t)(base_out + mm) * ncols + n] = pack_split_f32(a);
      }
    }
  }
}

// ---------------------------------------------------------------- down MFMA
// Block: 128 rows x 64 out cols. A = packed split act plane, B = fp32 weights.
template<bool SCATTER>
__global__ __launch_bounds__(256) void down_kernel(
    const uint* __restrict__ actp, const float* __restrict__ wd,
    const int* __restrict__ counts, const int* __restrict__ offsets,
    const int* __restrict__ etok, const float* __restrict__ ewt,
    float* __restrict__ out, int kdim) {
  int e = SCATTER ? blockIdx.z : 0;
  int cnt = SCATTER ? counts[e] : N_TOK;
  int m0 = blockIdx.x * 128;
  if (m0 >= cnt) return;
  int o0 = blockIdx.y * 64;

  __shared__ uint Ah[128][20], Al[128][20];
  __shared__ uint Bh[64][20], Bl[64][20];

  int tid = threadIdx.x;
  int arow = tid >> 1, ahalf = tid & 1;
  int srow = m0 + arow;
  int base_row = SCATTER ? offsets[e] : 0;
  int crow = SCATTER ? (srow < cnt ? srow : 0) : srow;
  const uint* aptr = actp + (size_t)(base_row + crow) * kdim + ahalf * 16;

  int brow = tid >> 2, bq = tid & 3;
  const float* wbase = SCATTER ? wd + (size_t)e * H_DIM * I_DIM : wd;
  const float* bptr = wbase + (size_t)(o0 + brow) * kdim + bq * 8;

  int w = tid >> 6, wr = w >> 1, wc = w & 1;
  int l = tid & 63, lr = l & 15, lk = l >> 4;

  f32x4 zf = {0.f, 0.f, 0.f, 0.f};
  f32x4 acc[4][2];
#pragma unroll
  for (int mi = 0; mi < 4; ++mi)
#pragma unroll
    for (int ni = 0; ni < 2; ++ni) acc[mi][ni] = zf;

  uint4 areg[4]; float4 breg[2];
#pragma unroll
  for (int q = 0; q < 4; ++q) areg[q] = *(const uint4*)(aptr + q * 4);
  breg[0] = *(const float4*)(bptr);
  breg[1] = *(const float4*)(bptr + 4);

  for (int k0 = 0; k0 < kdim; k0 += 32) {
    __syncthreads();
    {
      uint4 H0, L0, H1, L1;
      unpack8(areg[0], areg[1], H0, L0);
      unpack8(areg[2], areg[3], H1, L1);
      *(uint4*)&Ah[arow][ahalf * 8]     = H0;
      *(uint4*)&Ah[arow][ahalf * 8 + 4] = H1;
      *(uint4*)&Al[arow][ahalf * 8]     = L0;
      *(uint4*)&Al[arow][ahalf * 8 + 4] = L1;
      uint4 BH, BL;
      split8(breg[0], breg[1], BH, BL);
      *(uint4*)&Bh[brow][bq * 4] = BH;
      *(uint4*)&Bl[brow][bq * 4] = BL;
    }
    __syncthreads();
    if (k0 + 32 < kdim) {
#pragma unroll
      for (int q = 0; q < 4; ++q)
        areg[q] = *(const uint4*)(aptr + k0 + 32 + q * 4);
      breg[0] = *(const float4*)(bptr + k0 + 32);
      breg[1] = *(const float4*)(bptr + k0 + 36);
    }
    bf16x8 ah[4], al[4];
#pragma unroll
    for (int mi = 0; mi < 4; ++mi) {
      ah[mi] = ldfrag(&Ah[wr * 64 + mi * 16 + lr][lk * 4]);
      al[mi] = ldfrag(&Al[wr * 64 + mi * 16 + lr][lk * 4]);
    }
#pragma unroll
    for (int ni = 0; ni < 2; ++ni) {
      int br = wc * 32 + ni * 16 + lr;
      bf16x8 bh = ldfrag(&Bh[br][lk * 4]);
      bf16x8 bl = ldfrag(&Bl[br][lk * 4]);
#pragma unroll
      for (int mi = 0; mi < 4; ++mi) {
        acc[mi][ni] = MFMA16(ah[mi], bh, acc[mi][ni]);
        acc[mi][ni] = MFMA16(ah[mi], bl, acc[mi][ni]);
        acc[mi][ni] = MFMA16(al[mi], bh, acc[mi][ni]);
      }
    }
  }

#pragma unroll
  for (int mi = 0; mi < 4; ++mi) {
#pragma unroll
    for (int ni = 0; ni < 2; ++ni) {
      int n = o0 + wc * 32 + ni * 16 + lr;
#pragma unroll
      for (int r = 0; r < 4; ++r) {
        int mm = m0 + wr * 64 + mi * 16 + lk * 4 + r;
        if (!SCATTER) {
          out[(size_t)mm * H_DIM + n] = acc[mi][ni][r];
        } else if (mm < cnt) {
          int tok = etok[e * N_TOK + mm];
          float wt = ewt[e * N_TOK + mm];
          atomicAdd(&out[(size_t)tok * H_DIM + n], wt * acc[mi][ni][r]);
        }
      }
    }
  }
}

// ---------------------------------------------------------------- launch

extern "C" void kernel_launch(void* const* d_in, const int* in_sizes, int n_in,
                              void* d_out, int out_size, void* d_ws, size_t ws_size,
                              hipStream_t stream) {
  const float* x      = (const float*)d_in[0];
  const float* gate_w = (const float*)d_in[1];
  const float* eg     = (const float*)d_in[2];
  const float* eu     = (const float*)d_in[3];
  const float* ed     = (const float*)d_in[4];
  const float* sg     = (const float*)d_in[5];
  const float* su     = (const float*)d_in[6];
  const float* sd     = (const float*)d_in[7];
  float* out = (float*)d_out;

  char* ws = (char*)d_ws;
  int*   counts  = (int*)ws;                                  // 32 B
  int*   offsets = (int*)(ws + 64);                           // 32 B
  int*   etok    = (int*)(ws + 128);                          // 32 KiB
  float* ewt     = (float*)(ws + 128 + E_NUM * N_TOK * 4);    // 32 KiB
  uint*  px      = (uint*)(ws + (1 << 16));                   // 8 MB packed x
  uint*  acts    = px + (size_t)N_TOK * H_DIM;                // 11.5 MB packed shared act
  uint*  actr    = acts + (size_t)N_TOK * ISH;                // 11.5 MB packed routed act

  zero_counts_kernel<<<1, 64, 0, stream>>>(counts);
  split_x_kernel<<<(N_TOK * H_DIM / 4) / 256, 256, 0, stream>>>(x, px);
  router_kernel<<<N_TOK / 4, 256, 0, stream>>>(x, gate_w, counts, etok, ewt);
  prefix_kernel<<<1, 64, 0, stream>>>(counts, offsets);

  gateup_kernel<false><<<dim3(N_TOK / 128, ISH / 64), 256, 0, stream>>>(
      px, sg, su, counts, offsets, etok, acts, ISH);
  gateup_kernel<true><<<dim3(N_TOK / 128, I_DIM / 64, E_NUM), 256, 0, stream>>>(
      px, eg, eu, counts, offsets, etok, actr, I_DIM);
  down_kernel<false><<<dim3(N_TOK / 128, H_DIM / 64), 256, 0, stream>>>(
      acts, sd, counts, offsets, etok, ewt, out, ISH);
  down_kernel<true><<<dim3(N_TOK / 128, H_DIM / 64, E_NUM), 256, 0, stream>>>(
      actr, ed, counts, offsets, etok, ewt, out, I_DIM);
}

// Round 4
// 749.783 us; speedup vs baseline: 3.0913x; 1.3881x over previous
//
#include <hip/hip_runtime.h>
#include <hip/hip_bf16.h>
#include <stdint.h>

#define H_DIM 2048
#define I_DIM 1408
#define E_NUM 8
#define N_TOK 1024
#define ISH   2816

typedef short bf16x8 __attribute__((ext_vector_type(8)));
typedef float f32x4  __attribute__((ext_vector_type(4)));
typedef unsigned short ushort_t;

#define MFMA16(a,b,c) __builtin_amdgcn_mfma_f32_16x16x32_bf16((a),(b),(c),0,0,0)

// ---------------- split helpers: f = hi(bf16 trunc) + lo(bf16 trunc), rel err ~2^-16
__device__ __forceinline__ void split_pair(float f0, float f1, uint& hp, uint& lp) {
  uint b0 = __float_as_uint(f0), b1 = __float_as_uint(f1);
  uint h0 = b0 & 0xffff0000u, h1 = b1 & 0xffff0000u;
  float l0 = f0 - __uint_as_float(h0);
  float l1 = f1 - __uint_as_float(h1);
  hp = (b0 >> 16) | h1;
  lp = (__float_as_uint(l0) >> 16) | (__float_as_uint(l1) & 0xffff0000u);
}
__device__ __forceinline__ void split8(float4 a, float4 b, uint4& H, uint4& L) {
  split_pair(a.x, a.y, H.x, L.x);
  split_pair(a.z, a.w, H.y, L.y);
  split_pair(b.x, b.y, H.z, L.z);
  split_pair(b.z, b.w, H.w, L.w);
}

// swizzled in-tile byte offset for (local row r, logical 16B slot s); tile = 64 rows x 32 bf16
// slot' = (s + (r>>1)) & 3  -> 8 consecutive lanes hit 8 distinct 16B slots (conflict-free b128)
__device__ __forceinline__ int swz_off(int r, int s) {
  return (r << 6) + (((s + (r >> 1)) & 3) << 4);
}

// async global->LDS, 16B per lane; lds base wave-uniform, gptr per-lane
__device__ __forceinline__ void async_ld16(void* lds, const void* g) {
  __builtin_amdgcn_global_load_lds(
      (const __attribute__((address_space(1))) void*)g,
      (__attribute__((address_space(3))) void*)lds, 16, 0, 0);
}

// ---------------------------------------------------------------- tiny kernels
__global__ void zero_counts_kernel(int* counts) {
  if (threadIdx.x < E_NUM) counts[threadIdx.x] = 0;
}

// Split fp32 [R][K] into tiled bf16 hi/lo planes. Tile = 64x32, stored such that a
// linear 4KB global_load_lds fill reproduces the swizzled LDS image.
__global__ __launch_bounds__(256) void presplit_kernel(
    const float* __restrict__ src, ushort_t* __restrict__ hi,
    ushort_t* __restrict__ lo, int K, int KT, int write_lo) {
  int t = blockIdx.x, w = threadIdx.x;
  int r = w >> 2, sw = w & 3;
  int s = (sw - (r >> 1)) & 3;             // logical slot stored at position sw
  int rt = t / KT, kt = t - rt * KT;
  const float* p = src + (size_t)(rt * 64 + r) * K + kt * 32 + s * 8;
  float4 v0 = *(const float4*)p;
  float4 v1 = *(const float4*)(p + 4);
  uint4 HH, LL;
  split8(v0, v1, HH, LL);
  size_t base = ((size_t)t << 11) + ((size_t)w << 3);   // ushorts
  *(uint4*)(hi + base) = HH;
  if (write_lo) *(uint4*)(lo + base) = LL;
}

// ---------------------------------------------------------------- router
__global__ __launch_bounds__(256) void router_kernel(
    const float* __restrict__ x, const float* __restrict__ gate_w,
    int* __restrict__ counts, int* __restrict__ etok, float* __restrict__ ewt) {
  int token = blockIdx.x * 4 + (threadIdx.x >> 6);
  int lane  = threadIdx.x & 63;
  const float* xr = x + (size_t)token * H_DIM;
  float xs[H_DIM / 64];
#pragma unroll
  for (int j = 0; j < H_DIM / 64; ++j) xs[j] = xr[lane + 64 * j];
  float logits[E_NUM];
#pragma unroll
  for (int e = 0; e < E_NUM; ++e) {
    const float* wp = gate_w + (size_t)e * H_DIM;
    float s = 0.f;
#pragma unroll
    for (int j = 0; j < H_DIM / 64; ++j) s += xs[j] * wp[lane + 64 * j];
#pragma unroll
    for (int off = 32; off > 0; off >>= 1) s += __shfl_down(s, off, 64);
    logits[e] = s;
  }
  if (lane == 0) {
    float mx = logits[0];
    for (int e = 1; e < E_NUM; ++e) mx = fmaxf(mx, logits[e]);
    float p[E_NUM], se = 0.f;
    for (int e = 0; e < E_NUM; ++e) { p[e] = expf(logits[e] - mx); se += p[e]; }
    float inv_se = 1.f / se;
    for (int e = 0; e < E_NUM; ++e) p[e] *= inv_se;
    int i0 = 0;
    for (int e = 1; e < E_NUM; ++e) if (p[e] > p[i0]) i0 = e;
    int i1 = (i0 == 0) ? 1 : 0;
    for (int e = 0; e < E_NUM; ++e) { if (e == i0) continue; if (p[e] > p[i1]) i1 = e; }
    float w0 = p[i0], w1 = p[i1];
    float inv = 1.f / (w0 + w1 + 1e-20f);
    w0 *= inv; w1 *= inv;
    int s0 = atomicAdd(&counts[i0], 1);
    etok[i0 * N_TOK + s0] = token; ewt[i0 * N_TOK + s0] = w0;
    int s1 = atomicAdd(&counts[i1], 1);
    etok[i1 * N_TOK + s1] = token; ewt[i1 * N_TOK + s1] = w1;
  }
}

// ---------------------------------------------------------------- gate/up GEMM
// Block = 64 tokens x 64 cols of BOTH gate and up; fused silu*u epilogue writes
// act planes (split hi/lo, tiled+swizzled) for the down GEMM.
template<bool GATHER, int NT>
__global__ __launch_bounds__(256) void gateup_kernel(
    const ushort_t* __restrict__ axh, const ushort_t* __restrict__ axl,
    const ushort_t* __restrict__ bgh, const ushort_t* __restrict__ bgl,
    const ushort_t* __restrict__ buh, const ushort_t* __restrict__ bul,
    const int* __restrict__ counts, const int* __restrict__ etok,
    ushort_t* __restrict__ outh, ushort_t* __restrict__ outl, int ncols) {
  constexpr int NB   = (NT == 3) ? 4 : 2;   // B planes staged
  constexpr int NPL  = 2 + NB;              // planes per buffer (A hi/lo + B)
  constexpr int BUFB = NPL * 4096;
  constexpr int NCH  = GATHER ? NB * 4 : NPL * 4;  // 1KB staging chunks per iter
  constexpr int CPW  = NCH / 4;
  const int KT = H_DIM / 32;

  __shared__ __align__(16) char smem[2 * (2 + ((NT == 3) ? 4 : 2)) * 4096];

  // bijective XCD swizzle (grid divisible by 8): XCD k gets a contiguous chunk
  int nwg = gridDim.x * gridDim.y * gridDim.z;
  int flat = blockIdx.x + gridDim.x * (blockIdx.y + gridDim.y * blockIdx.z);
  int o = (flat & 7) * (nwg >> 3) + (flat >> 3);
  int bx = o % gridDim.x; int rest = o / gridDim.x;
  int by = rest % gridDim.y; int e = rest / gridDim.y;

  int m0 = bx * 64, o0 = by * 64;
  int cnt = GATHER ? counts[e] : N_TOK;
  if (GATHER && m0 >= cnt) return;

  const int tid = threadIdx.x;
  const int w = tid >> 6, l = tid & 63;

  // staging source/dest setup
  const ushort_t* gsrc[CPW];
  int ldst[CPW];
#pragma unroll
  for (int i = 0; i < CPW; ++i) {
    int c = w * CPW + i;
    int p = GATHER ? (c >> 2) + 2 : (c >> 2);
    int q = c & 3;
    const ushort_t* base;
    size_t rt;
    if (p == 0)      { base = axh; rt = (size_t)(m0 >> 6); }
    else if (p == 1) { base = axl; rt = (size_t)(m0 >> 6); }
    else {
      int bp = p - 2;
      rt = (size_t)(((GATHER ? e * I_DIM : 0) + o0) >> 6);
      if (NT == 3) base = (bp == 0) ? bgh : (bp == 1) ? bgl : (bp == 2) ? buh : bul;
      else         base = (bp == 0) ? bgh : buh;
    }
    gsrc[i] = base + rt * (size_t)KT * 2048 + q * 512 + l * 8;
    ldst[i] = p * 4096 + q * 1024;
  }

  // gathered-A setup (routed): one 16B chunk per thread per plane per iter
  int gr = tid >> 2, gs = tid & 3;
  int awz = swz_off(gr, gs);
  size_t aoff = 0;
  if (GATHER) {
    int srow = m0 + gr; if (srow >= cnt) srow = cnt - 1;
    int tok = etok[e * N_TOK + srow];
    aoff = ((size_t)((tok >> 6) * KT) << 11) + (swz_off(tok & 63, gs) >> 1);
  }

  // prologue: stage tile 0 into buf 0
  if (GATHER) {
    uint4 hv = *(const uint4*)(axh + aoff);
    uint4 lv = *(const uint4*)(axl + aoff);
    *(uint4*)(smem + awz) = hv;
    *(uint4*)(smem + 4096 + awz) = lv;
  }
#pragma unroll
  for (int i = 0; i < CPW; ++i) async_ld16(smem + ldst[i], gsrc[i]);
  __syncthreads();

  int wr = w & 1, wc = w >> 1, lr = l & 15, lk = l >> 4;
  f32x4 accg[2][2], accu[2][2];
#pragma unroll
  for (int mi = 0; mi < 2; ++mi)
#pragma unroll
    for (int nj = 0; nj < 2; ++nj) {
      accg[mi][nj] = (f32x4){0.f, 0.f, 0.f, 0.f};
      accu[mi][nj] = (f32x4){0.f, 0.f, 0.f, 0.f};
    }

  for (int kt = 0; kt < KT; ++kt) {
    int cur = kt & 1;
    char* bp_ = smem + cur * BUFB;
    char* nb_ = smem + (cur ^ 1) * BUFB;
    uint4 hv, lv;
    if (kt + 1 < KT) {
#pragma unroll
      for (int i = 0; i < CPW; ++i)
        async_ld16(nb_ + ldst[i], gsrc[i] + (size_t)(kt + 1) * 2048);
      if (GATHER) {
        hv = *(const uint4*)(axh + aoff + (size_t)(kt + 1) * 2048);
        lv = *(const uint4*)(axl + aoff + (size_t)(kt + 1) * 2048);
      }
    }
    bf16x8 ah[2], al[2];
#pragma unroll
    for (int mi = 0; mi < 2; ++mi) {
      int fr = wr * 32 + mi * 16 + lr;
      ah[mi] = *(const bf16x8*)(bp_ + 0 * 4096 + swz_off(fr, lk));
      al[mi] = *(const bf16x8*)(bp_ + 1 * 4096 + swz_off(fr, lk));
    }
#pragma unroll
    for (int nj = 0; nj < 2; ++nj) {
      int fr = wc * 32 + nj * 16 + lr;
      bf16x8 Bgh = *(const bf16x8*)(bp_ + 2 * 4096 + swz_off(fr, lk));
      bf16x8 Buh = *(const bf16x8*)(bp_ + ((NT == 3) ? 4 : 3) * 4096 + swz_off(fr, lk));
      bf16x8 Bgl, Bul;
      if (NT == 3) {
        Bgl = *(const bf16x8*)(bp_ + 3 * 4096 + swz_off(fr, lk));
        Bul = *(const bf16x8*)(bp_ + 5 * 4096 + swz_off(fr, lk));
      }
#pragma unroll
      for (int mi = 0; mi < 2; ++mi) {
        accg[mi][nj] = MFMA16(ah[mi], Bgh, accg[mi][nj]);
        accu[mi][nj] = MFMA16(ah[mi], Buh, accu[mi][nj]);
        if (NT == 3) {
          accg[mi][nj] = MFMA16(ah[mi], Bgl, accg[mi][nj]);
          accu[mi][nj] = MFMA16(ah[mi], Bul, accu[mi][nj]);
        }
        accg[mi][nj] = MFMA16(al[mi], Bgh, accg[mi][nj]);
        accu[mi][nj] = MFMA16(al[mi], Buh, accu[mi][nj]);
      }
    }
    if (GATHER && kt + 1 < KT) {
      *(uint4*)(nb_ + awz) = hv;
      *(uint4*)(nb_ + 4096 + awz) = lv;
    }
    __syncthreads();
  }

  // ---- epilogue: silu(g)*u, transpose via LDS, write split tiled act planes
  float* tr = (float*)smem;   // [64][68]
#pragma unroll
  for (int mi = 0; mi < 2; ++mi)
#pragma unroll
    for (int nj = 0; nj < 2; ++nj) {
      int col = wc * 32 + nj * 16 + lr;
#pragma unroll
      for (int r2 = 0; r2 < 4; ++r2) {
        int row = wr * 32 + mi * 16 + lk * 4 + r2;
        float g = accg[mi][nj][r2], u = accu[mi][nj][r2];
        tr[row * 68 + col] = (g / (1.f + expf(-g))) * u;
      }
    }
  __syncthreads();
  {
    int r = tid >> 2, s4 = tid & 3;
    size_t baserow = (GATHER ? (size_t)e * N_TOK : 0) + (size_t)m0;
    size_t ort = baserow >> 6;
    int OKT = ncols >> 5;
#pragma unroll
    for (int h = 0; h < 2; ++h) {
      int ss = s4 + h * 4;
      int ktile = (o0 >> 5) + (ss >> 2);
      int sit = ss & 3;
      const float* pr = tr + r * 68 + ss * 8;
      float4 v0 = *(const float4*)pr;
      float4 v1 = *(const float4*)(pr + 4);
      uint4 HH, LL;
      split8(v0, v1, HH, LL);
      size_t dst = ((size_t)(ort * OKT + ktile) << 11) + (swz_off(r, sit) >> 1);
      *(uint4*)(outh + dst) = HH;
      *(uint4*)(outl + dst) = LL;
    }
  }
}

// ---------------------------------------------------------------- down GEMM
template<bool SCATTER, int NT>
__global__ __launch_bounds__(256) void down_kernel(
    const ushort_t* __restrict__ axh, const ushort_t* __restrict__ axl,
    const ushort_t* __restrict__ bh_, const ushort_t* __restrict__ bl_,
    const int* __restrict__ counts, const int* __restrict__ etok,
    const float* __restrict__ ewt, float* __restrict__ out, int Kd) {
  constexpr int NPL  = (NT == 3) ? 4 : 3;   // Ah, Al, Bh[, Bl]
  constexpr int BUFB = NPL * 4096;
  constexpr int NCH  = NPL * 4;
  constexpr int CPW  = NCH / 4;
  const int KT = Kd >> 5;

  __shared__ __align__(16) char smem[2 * ((NT == 3) ? 4 : 3) * 4096];

  int nwg = gridDim.x * gridDim.y * gridDim.z;
  int flat = blockIdx.x + gridDim.x * (blockIdx.y + gridDim.y * blockIdx.z);
  int o = (flat & 7) * (nwg >> 3) + (flat >> 3);
  int bx = o % gridDim.x; int rest = o / gridDim.x;
  int by = rest % gridDim.y; int e = rest / gridDim.y;

  int m0 = bx * 64, o0 = by * 64;
  int cnt = SCATTER ? counts[e] : N_TOK;
  if (SCATTER && m0 >= cnt) return;

  const int tid = threadIdx.x;
  const int w = tid >> 6, l = tid & 63;

  const ushort_t* gsrc[CPW];
  int ldst[CPW];
#pragma unroll
  for (int i = 0; i < CPW; ++i) {
    int c = w * CPW + i;
    int p = c >> 2, q = c & 3;
    const ushort_t* base;
    size_t rt;
    if (p == 0)      { base = axh; rt = (size_t)(((SCATTER ? e * N_TOK : 0) + m0) >> 6); }
    else if (p == 1) { base = axl; rt = (size_t)(((SCATTER ? e * N_TOK : 0) + m0) >> 6); }
    else {
      rt = (size_t)(((SCATTER ? e * H_DIM : 0) + o0) >> 6);
      base = (p == 2) ? bh_ : bl_;
    }
    gsrc[i] = base + rt * (size_t)KT * 2048 + q * 512 + l * 8;
    ldst[i] = p * 4096 + q * 1024;
  }

#pragma unroll
  for (int i = 0; i < CPW; ++i) async_ld16(smem + ldst[i], gsrc[i]);
  __syncthreads();

  int wr = w & 1, wc = w >> 1, lr = l & 15, lk = l >> 4;
  f32x4 acc[2][2];
#pragma unroll
  for (int mi = 0; mi < 2; ++mi)
#pragma unroll
    for (int nj = 0; nj < 2; ++nj) acc[mi][nj] = (f32x4){0.f, 0.f, 0.f, 0.f};

  for (int kt = 0; kt < KT; ++kt) {
    int cur = kt & 1;
    char* bp_ = smem + cur * BUFB;
    if (kt + 1 < KT) {
      char* nb_ = smem + (cur ^ 1) * BUFB;
#pragma unroll
      for (int i = 0; i < CPW; ++i)
        async_ld16(nb_ + ldst[i], gsrc[i] + (size_t)(kt + 1) * 2048);
    }
    bf16x8 ah[2], al[2];
#pragma unroll
    for (int mi = 0; mi < 2; ++mi) {
      int fr = wr * 32 + mi * 16 + lr;
      ah[mi] = *(const bf16x8*)(bp_ + 0 * 4096 + swz_off(fr, lk));
      al[mi] = *(const bf16x8*)(bp_ + 1 * 4096 + swz_off(fr, lk));
    }
#pragma unroll
    for (int nj = 0; nj < 2; ++nj) {
      int fr = wc * 32 + nj * 16 + lr;
      bf16x8 Bh = *(const bf16x8*)(bp_ + 2 * 4096 + swz_off(fr, lk));
      bf16x8 Bl;
      if (NT == 3) Bl = *(const bf16x8*)(bp_ + 3 * 4096 + swz_off(fr, lk));
#pragma unroll
      for (int mi = 0; mi < 2; ++mi) {
        acc[mi][nj] = MFMA16(ah[mi], Bh, acc[mi][nj]);
        if (NT == 3) acc[mi][nj] = MFMA16(ah[mi], Bl, acc[mi][nj]);
        acc[mi][nj] = MFMA16(al[mi], Bh, acc[mi][nj]);
      }
    }
    __syncthreads();
  }

#pragma unroll
  for (int mi = 0; mi < 2; ++mi)
#pragma unroll
    for (int nj = 0; nj < 2; ++nj) {
      int col = o0 + wc * 32 + nj * 16 + lr;
#pragma unroll
      for (int r2 = 0; r2 < 4; ++r2) {
        int srow = wr * 32 + mi * 16 + lk * 4 + r2;
        float v = acc[mi][nj][r2];
        if (!SCATTER) {
          out[(size_t)(m0 + srow) * H_DIM + col] = v;
        } else {
          int slot = m0 + srow;
          if (slot < cnt) {
            int tok = etok[e * N_TOK + slot];
            float wt = ewt[e * N_TOK + slot];
            atomicAdd(&out[(size_t)tok * H_DIM + col], wt * v);
          }
        }
      }
    }
}

// ---------------------------------------------------------------- launch
extern "C" void kernel_launch(void* const* d_in, const int* in_sizes, int n_in,
                              void* d_out, int out_size, void* d_ws, size_t ws_size,
                              hipStream_t stream) {
  const float* x      = (const float*)d_in[0];
  const float* gate_w = (const float*)d_in[1];
  const float* eg     = (const float*)d_in[2];
  const float* eu     = (const float*)d_in[3];
  const float* ed     = (const float*)d_in[4];
  const float* sg     = (const float*)d_in[5];
  const float* su     = (const float*)d_in[6];
  const float* sd     = (const float*)d_in[7];
  float* out = (float*)d_out;

  char* ws = (char*)d_ws;
  size_t off = 0;
  auto carve = [&](size_t n) { char* p = ws + off; off += (n + 255) & ~(size_t)255; return p; };

  int*   counts = (int*)carve(E_NUM * 4);
  int*   etok   = (int*)carve((size_t)E_NUM * N_TOK * 4);
  float* ewt    = (float*)carve((size_t)E_NUM * N_TOK * 4);
  ushort_t* pxh  = (ushort_t*)carve((size_t)N_TOK * H_DIM * 2);
  ushort_t* pxl  = (ushort_t*)carve((size_t)N_TOK * H_DIM * 2);
  ushort_t* acth = (ushort_t*)carve((size_t)N_TOK * ISH * 2);
  ushort_t* actl = (ushort_t*)carve((size_t)N_TOK * ISH * 2);
  ushort_t* arth = (ushort_t*)carve((size_t)E_NUM * N_TOK * I_DIM * 2);
  ushort_t* artl = (ushort_t*)carve((size_t)E_NUM * N_TOK * I_DIM * 2);
  // hi weight planes (NT2 prefix)
  ushort_t* sgh = (ushort_t*)carve((size_t)ISH * H_DIM * 2);
  ushort_t* suh = (ushort_t*)carve((size_t)ISH * H_DIM * 2);
  ushort_t* sdh = (ushort_t*)carve((size_t)H_DIM * ISH * 2);
  ushort_t* egh = (ushort_t*)carve((size_t)E_NUM * I_DIM * H_DIM * 2);
  ushort_t* euh = (ushort_t*)carve((size_t)E_NUM * I_DIM * H_DIM * 2);
  ushort_t* edh = (ushort_t*)carve((size_t)E_NUM * H_DIM * I_DIM * 2);
  // lo weight planes (NT3 only)
  ushort_t* sgl = (ushort_t*)carve((size_t)ISH * H_DIM * 2);
  ushort_t* sul = (ushort_t*)carve((size_t)ISH * H_DIM * 2);
  ushort_t* sdl = (ushort_t*)carve((size_t)H_DIM * ISH * 2);
  ushort_t* egl = (ushort_t*)carve((size_t)E_NUM * I_DIM * H_DIM * 2);
  ushort_t* eul = (ushort_t*)carve((size_t)E_NUM * I_DIM * H_DIM * 2);
  ushort_t* edl = (ushort_t*)carve((size_t)E_NUM * H_DIM * I_DIM * 2);
  size_t need3 = off;
  int nt3 = (ws_size >= need3) ? 1 : 0;

  zero_counts_kernel<<<1, 64, 0, stream>>>(counts);
  router_kernel<<<N_TOK / 4, 256, 0, stream>>>(x, gate_w, counts, etok, ewt);

  // presplit: x always hi+lo; weights lo only for NT3
  presplit_kernel<<<(N_TOK / 64) * (H_DIM / 32), 256, 0, stream>>>(x, pxh, pxl, H_DIM, H_DIM / 32, 1);
  presplit_kernel<<<(ISH / 64) * (H_DIM / 32), 256, 0, stream>>>(sg, sgh, sgl, H_DIM, H_DIM / 32, nt3);
  presplit_kernel<<<(ISH / 64) * (H_DIM / 32), 256, 0, stream>>>(su, suh, sul, H_DIM, H_DIM / 32, nt3);
  presplit_kernel<<<(H_DIM / 64) * (ISH / 32), 256, 0, stream>>>(sd, sdh, sdl, ISH, ISH / 32, nt3);
  presplit_kernel<<<(E_NUM * I_DIM / 64) * (H_DIM / 32), 256, 0, stream>>>(eg, egh, egl, H_DIM, H_DIM / 32, nt3);
  presplit_kernel<<<(E_NUM * I_DIM / 64) * (H_DIM / 32), 256, 0, stream>>>(eu, euh, eul, H_DIM, H_DIM / 32, nt3);
  presplit_kernel<<<(E_NUM * H_DIM / 64) * (I_DIM / 32), 256, 0, stream>>>(ed, edh, edl, I_DIM, I_DIM / 32, nt3);

  if (nt3) {
    gateup_kernel<false, 3><<<dim3(N_TOK / 64, ISH / 64), 256, 0, stream>>>(
        pxh, pxl, sgh, sgl, suh, sul, counts, etok, acth, actl, ISH);
    gateup_kernel<true, 3><<<dim3(N_TOK / 64, I_DIM / 64, E_NUM), 256, 0, stream>>>(
        pxh, pxl, egh, egl, euh, eul, counts, etok, arth, artl, I_DIM);
    down_kernel<false, 3><<<dim3(N_TOK / 64, H_DIM / 64), 256, 0, stream>>>(
        acth, actl, sdh, sdl, counts, etok, ewt, out, ISH);
    down_kernel<true, 3><<<dim3(N_TOK / 64, H_DIM / 64, E_NUM), 256, 0, stream>>>(
        arth, artl, edh, edl, counts, etok, ewt, out, I_DIM);
  } else {
    gateup_kernel<false, 2><<<dim3(N_TOK / 64, ISH / 64), 256, 0, stream>>>(
        pxh, pxl, sgh, sgh, suh, suh, counts, etok, acth, actl, ISH);
    gateup_kernel<true, 2><<<dim3(N_TOK / 64, I_DIM / 64, E_NUM), 256, 0, stream>>>(
        pxh, pxl, egh, egh, euh, euh, counts, etok, arth, artl, I_DIM);
    down_kernel<false, 2><<<dim3(N_TOK / 64, H_DIM / 64), 256, 0, stream>>>(
        acth, actl, sdh, sdh, counts, etok, ewt, out, ISH);
    down_kernel<true, 2><<<dim3(N_TOK / 64, H_DIM / 64, E_NUM), 256, 0, stream>>>(
        arth, artl, edh, edh, counts, etok, ewt, out, I_DIM);
  }
}